// Round 5
// baseline (220.273 us; speedup 1.0000x reference)
//
#include <hip/hip_runtime.h>

// MakeCutouts: 32 cutouts of (8,3,512,512) fp32 -> adaptive avg pool 224x224.
//
// R8: R7 showed VALU was not the binder (~62us/dispatch vs ~25-30us sum-of-
// floors): the kernel was overlap-bound -- 84 short blocks/CU, each with a
// full vmcnt(0)-draining __syncthreads between stage and pool. Restructure:
// one PERSISTENT block per (plane, cutout) = 768 blocks (3/CU), looping over
// all 28 bands with a double-buffered tile. Steady state per band:
//   ds_write(band k+1, from regs)  |  issue global loads(band k+2)  |
//   pool(band k)  ->  barrier waiting ONLY lgkmcnt(0)
// (inline asm + raw s_barrier: prefetched global loads stay in flight across
// the barrier; loads get a whole pool phase to land). Pool params (sq, wq,
// weights, base) computed ONCE per block instead of per band. XCD chunking
// keeps all 32 cutouts of a plane co-resident on one XCD (3MB in 4MB L2).
// Stage is SALU-scalarized (readfirstlane wave id) as in R7.

typedef float f32x4 __attribute__((ext_vector_type(4)));

constexpr int OUTSZ = 224;
constexpr int BB    = 8;
constexpr int CC    = 3;
constexpr int HH    = 512;
constexpr int WW    = 512;
constexpr int CUTN  = 32;

constexpr int TP     = 8;             // output rows per band
constexpr int NBAND  = OUTSZ / TP;    // 28
constexpr int TILEF  = TP * WW + 8;   // 4104 floats/buffer; pad for masked reads
constexpr int NPLANE = BB * CC;                 // 24
constexpr int NBLOCKS = NPLANE * CUTN;          // 768 = 8 * 96
constexpr int NXCD   = 8;
constexpr int CHUNK  = NBLOCKS / NXCD;          // 96 = 3 planes * 32 cutouts

// Issue the global loads for one band into named regs (T14 issue-early).
// wv is wave-uniform (readfirstlane'd): rs/wp/row-base on SALU, loads under
// uniform s_cbranch. Unloaded v[j][m] are stale but never consumed (same wp
// recomputed at write time). All indices compile-time after unroll.
__device__ __forceinline__ void stage_issue(const float* __restrict__ plane_p,
                                            int S, int p0, int wv, int vo,
                                            f32x4 (&v)[4][4])
{
#pragma unroll
    for (int j = 0; j < 4; ++j) {
        int k  = (wv >> 1) + 2 * j;                        // scalar 0..7
        int p  = p0 + k;
        int rs = (p * S) / OUTSZ;                          // scalar magic div
        int wp = ((p + 1) * S + OUTSZ - 1) / OUTSZ - rs;   // 1..4, scalar
        const f32x4* rp = (const f32x4*)(plane_p + (size_t)rs * WW);
        v[j][0] = rp[vo];
        if (wp > 1) v[j][1] = rp[vo + 128];
        if (wp > 2) v[j][2] = rp[vo + 256];
        if (wp > 3) v[j][3] = rp[vo + 384];
    }
}

// Reduce the prefetched rows (v_pk_add_f32 pairs), scale by 1/wp, write one
// 512-wide averaged row per output row into the tile buffer.
__device__ __forceinline__ void stage_write(float* __restrict__ buf,
                                            int S, int p0, int wv, int vo,
                                            f32x4 (&v)[4][4])
{
    f32x4* t4 = (f32x4*)buf;
#pragma unroll
    for (int j = 0; j < 4; ++j) {
        int k  = (wv >> 1) + 2 * j;
        int p  = p0 + k;
        int rs = (p * S) / OUTSZ;
        int wp = ((p + 1) * S + OUTSZ - 1) / OUTSZ - rs;   // 1..4, scalar
        f32x4 a = v[j][0];
        if (wp > 1) a += v[j][1];
        if (wp > 2) a += v[j][2];
        if (wp > 3) a += v[j][3];
        float iv = (wp == 1) ? 1.0f : (wp == 2) ? 0.5f
                 : (wp == 3) ? (1.0f / 3.0f) : 0.25f;      // scalar cselect
        a *= iv;
        t4[k * 128 + vo] = a;             // adjacent lanes -> ds_write_b128
    }
}

// Pool all TP rows of one band for this thread's fixed column: 3/4-term fma
// dot with weights {invq or 0}. Weight-0 reads hit finite staged data or the
// zeroed pad (row 7), so fma-with-0 is exact.
template <int WIN>
__device__ __forceinline__ void pool_band(const float* __restrict__ buf,
                                          float* __restrict__ outp,
                                          int base, const float* __restrict__ w)
{
#pragma unroll
    for (int k = 0; k < TP; ++k) {
        const float* tr = buf + k * WW + base;
        float s = tr[0] * w[0];           // adjacent cols -> ds_read2_b32
        s = fmaf(tr[1], w[1], s);
        s = fmaf(tr[2], w[2], s);
        if (WIN == 4) s = fmaf(tr[3], w[3], s);
        outp[(size_t)k * OUTSZ] = s;
    }
}

// lgkmcnt(0)-only barrier: LDS writes/reads visible, but global loads stay
// in flight (the whole point -- __syncthreads would drain vmcnt(0)).
__device__ __forceinline__ void band_barrier()
{
    asm volatile("s_waitcnt lgkmcnt(0)" ::: "memory");
    __builtin_amdgcn_s_barrier();
}

template <int WIN>
__device__ __forceinline__ void run_bands(const float* __restrict__ plane_p,
                                          float (*tile)[TILEF],
                                          float* __restrict__ outp,
                                          int S, int wv, int vo, int tid,
                                          int base, const float* __restrict__ wt,
                                          f32x4 (&v)[4][4])
{
    for (int k = 0; k < NBAND; ++k) {
        if (k + 1 < NBAND)                         // consume regs (band k+1)
            stage_write(tile[(k + 1) & 1], S, (k + 1) * TP, wv, vo, v);
        if (k + 2 < NBAND)                         // refill regs (band k+2)
            stage_issue(plane_p, S, (k + 2) * TP, wv, vo, v);
        if (tid < OUTSZ)                           // pool band k
            pool_band<WIN>(tile[k & 1], outp + (size_t)k * TP * OUTSZ, base, wt);
        band_barrier();
    }
}

__global__ __launch_bounds__(256, 3) void make_cutouts_kernel(
    const float* __restrict__ x,
    const int*   __restrict__ sizes,
    const int*   __restrict__ offy,
    const int*   __restrict__ offx,
    float*       __restrict__ out)
{
    __shared__ float tile[2][TILEF];   // 32832 B -> 4 blocks/CU cap; grid 3/CU

    // Bijective XCD chunk swizzle (768 = 8*96): XCD k owns planes [3k,3k+3),
    // cutout fastest -> all 32 cutouts of a plane co-resident on one XCD.
    int gid = blockIdx.x;
    int w   = (gid % NXCD) * CHUNK + gid / NXCD;
    int plane = w / CUTN;             // 0..23  (= b*CC + c)
    int i     = w - plane * CUTN;     // cutout 0..31
    int b     = plane / CC;
    int c     = plane - b * CC;

    // block-uniform per-cutout params -> scalar broadcast
    int S  = sizes[i];
    int y0 = offy[i];
    int x0 = offx[i];
    int tid = threadIdx.x;

    const float* plane_p = x + (size_t)(plane * HH + y0) * WW;

    // zero both pads once; stage writes exactly [0,4096) so they stay zero.
    if (tid < 8) {
        tile[0][TP * WW + tid] = 0.0f;
        tile[1][TP * WW + tid] = 0.0f;
    }

    int wv   = __builtin_amdgcn_readfirstlane(tid >> 6);  // 0..3
    int lane = tid & 63;
    int vo   = ((wv & 1) << 6) + lane;    // float4 col index 0..127

    // pool params: computed ONCE, reused for all 28 bands.
    int sq = (tid * S) / OUTSZ;
    int wq = ((tid + 1) * S + OUTSZ - 1) / OUTSZ - sq;     // 1..4
    float invq = (wq == 1) ? 1.0f : (wq == 2) ? 0.5f
               : (wq == 3) ? (1.0f / 3.0f) : 0.25f;
    float wt[4];
    wt[0] = invq;
    wt[1] = (wq > 1) ? invq : 0.0f;
    wt[2] = (wq > 2) ? invq : 0.0f;
    wt[3] = (wq > 3) ? invq : 0.0f;
    int base = x0 + sq;
    float* outp = out + ((size_t)((i * BB + b) * CC + c) * OUTSZ) * OUTSZ + tid;

    // prologue: band 0 staged synchronously; band 1 loads issued.
    f32x4 v[4][4];
    stage_issue(plane_p, S, 0, wv, vo, v);
    stage_write(tile[0], S, 0, wv, vo, v);
    stage_issue(plane_p, S, TP, wv, vo, v);
    band_barrier();

    if (S <= 2 * OUTSZ)   // block-uniform: max bin width 3
        run_bands<3>(plane_p, tile, outp, S, wv, vo, tid, base, wt, v);
    else                  // S in (448,512]: max bin width 4
        run_bands<4>(plane_p, tile, outp, S, wv, vo, tid, base, wt, v);
}

extern "C" void kernel_launch(void* const* d_in, const int* in_sizes, int n_in,
                              void* d_out, int out_size, void* d_ws, size_t ws_size,
                              hipStream_t stream) {
    const float* x     = (const float*)d_in[0];
    const int*   sizes = (const int*)d_in[1];
    const int*   offy  = (const int*)d_in[2];
    const int*   offx  = (const int*)d_in[3];
    float* out = (float*)d_out;

    make_cutouts_kernel<<<NBLOCKS, 256, 0, stream>>>(x, sizes, offy, offx, out);
}